// Round 11
// baseline (284.681 us; speedup 1.0000x reference)
//
#include <hip/hip_runtime.h>
#include <stdint.h>

// FFN: x[16384,1024] -> relu(x@W1^T+b1)[16384,4096] -> q_e4m3 -> @W2^T+b2 -> q_e5m10
// Round 13: fat waves to cut LDS bytes. r10 proved (occupancy 2x, time equal)
// that cost = serial(MFMA + LDS@~peak); overlap never materializes. So minimize
// the sum: per-wave tile 128x128 (acc=256 regs) -> LDS reads per output halve
// (2B vs 4B per out per BK64). 4-wave (256-thread) blocks, 256^2 tile, 1
// wave/SIMD, ~320-360 regs/wave (fits 4-5 waves/CU; NO launch_bounds cap).
// Model per 256^2-K64 tile: 2483 MFMA + (128KB rd + 64KB wr)/128B = 3983 cyc
// vs r9/r10's ~5150. Same dbuf barrier-light loop, same staging swizzle
// (re-parameterized to 32-row rounds for 256 threads), sched_barrier pin, no
// setprio. ks-outer MFMA sweep keeps per-element k0->k1 order -> bit-identical.

#define M_TOT 16384
#define D_DIM 1024
#define H_DIM 4096

typedef _Float16 f16x8 __attribute__((ext_vector_type(8)));
typedef _Float16 f16x4 __attribute__((ext_vector_type(4)));
typedef float f32x4 __attribute__((ext_vector_type(4)));
typedef int i32x4 __attribute__((ext_vector_type(4)));
typedef int i32x8 __attribute__((ext_vector_type(8)));

// global -> LDS direct copy, 16B per lane. LDS dest = wave-uniform base + lane*16.
__device__ __forceinline__ void gl16(const void* g, void* l) {
    __builtin_amdgcn_global_load_lds(
        (const __attribute__((address_space(1))) unsigned int*)(uintptr_t)g,
        (__attribute__((address_space(3))) unsigned int*)(unsigned int)(uintptr_t)l,
        16, 0, 0);
}

// positive-input e4m3 quantize (post-relu), division-free, RNE. Returns the
// quantized VALUE as f16 (exactly representable).
__device__ __forceinline__ _Float16 q_e4m3_pos(float v) {
    uint32_t t = __float_as_uint(v);
    uint32_t tn = (t + 0x7ffffu + ((t >> 20) & 1u)) & 0xfff00000u;
    float qn = __uint_as_float(tn);
    float qs = rintf(v * 512.0f) * 0.001953125f;
    return (_Float16)(v < 0.015625f ? qs : qn);
}

// ---- pre-pass: fp32 -> f16 (RNE), vectorized x4 ----
__global__ __launch_bounds__(256) void cvt_f16_kernel(
    const float* __restrict__ in, _Float16* __restrict__ out, int n4)
{
    int i = blockIdx.x * 256 + threadIdx.x;
    if (i >= n4) return;
    float4 v = reinterpret_cast<const float4*>(in)[i];
    f16x4 hv = {(_Float16)v.x, (_Float16)v.y, (_Float16)v.z, (_Float16)v.w};
    reinterpret_cast<f16x4*>(out)[i] = hv;
}

// ---- pre-pass: fp32 -> e4m3 BYTES via HW cvt (RNE, OCP grid == ref grid) ----
__global__ __launch_bounds__(256) void quant_e4m3_byte_kernel(
    const float* __restrict__ in, uint32_t* __restrict__ outq, int n4)
{
    int i = blockIdx.x * 256 + threadIdx.x;
    if (i >= n4) return;
    float4 v = reinterpret_cast<const float4*>(in)[i];
    uint32_t r = __builtin_amdgcn_cvt_pk_fp8_f32(v.x, v.y, 0, false);
    r = __builtin_amdgcn_cvt_pk_fp8_f32(v.z, v.w, r, true);
    outq[i] = r;
}

// ---- GEMM1: h=relu(xh@w1h^T+b1), q_e4m3, store BYTES. 256x256 BK=64 f16. ----
// 4 waves (2M x 2N) of 128x128. Dbuf 128KB LDS. Staging: 32-row x 128B rounds.
__global__ __launch_bounds__(256) void gemm1_f16(
    const _Float16* __restrict__ A, const _Float16* __restrict__ B,
    const float* __restrict__ bias, uint8_t* __restrict__ Cq)
{
    constexpr int K = D_DIM;   // 1024
    constexpr int N = H_DIM;   // 4096 (bytes per out row)
    __shared__ __align__(16) _Float16 smem[65536];   // 128 KiB
    _Float16* sA = smem;            // 2 x 16384
    _Float16* sB = smem + 32768;    // 2 x 16384

    const int tid  = threadIdx.x;
    const int lane = tid & 63;
    const int w    = tid >> 6;             // 4 waves
    const int wr   = w >> 1, wc = w & 1;   // per-wave C: 128 rows x 128 cols
    const int fr   = lane & 15, kq = lane >> 4;

    constexpr int NBX = N / 256;               // 16
    constexpr int NWG = (M_TOT / 256) * NBX;   // 1024
    constexpr int CPX = NWG / 8;
    int bid = blockIdx.y * NBX + blockIdx.x;
    bid = (bid & 7) * CPX + (bid >> 3);
    const int n0 = (bid % NBX) * 256;
    const int m0 = (bid / NBX) * 256;

    // staging: round = 32 rows x 128B = 4KB; 8 rounds per operand per tile.
    const int srow = tid >> 3;                   // 0..31 row-in-round
    const int sseg = (tid & 7) ^ (srow & 7);     // swizzled 16B slot
    const _Float16* gA = A + (size_t)(m0 + srow) * K + sseg * 8;
    const _Float16* gB = B + (size_t)(n0 + srow) * K + sseg * 8;
    const int ldsw = w * 512;                    // f16 per wave per round (1KB)

    const int xorv = fr & 7;
    const int cA0 = (kq ^ xorv) * 8;
    const int cA1 = ((kq + 4) ^ xorv) * 8;
    const int aRow = wr * 128 + fr;
    const int bRow = wc * 128 + fr;

    f32x4 acc[8][8];
#pragma unroll
    for (int i = 0; i < 8; i++)
#pragma unroll
        for (int j = 0; j < 8; j++) acc[i][j] = (f32x4){0.f, 0.f, 0.f, 0.f};

    constexpr int NK = K / 64;   // 16

    // prologue: stage tile 0 into buf0 (16 x gl16), drain, barrier.
#pragma unroll
    for (int g = 0; g < 8; g++) gl16(gB + (size_t)(32 * g) * K, sB + g * 2048 + ldsw);
#pragma unroll
    for (int g = 0; g < 8; g++) gl16(gA + (size_t)(32 * g) * K, sA + g * 2048 + ldsw);
    asm volatile("s_waitcnt vmcnt(0)" ::: "memory");
    __builtin_amdgcn_s_barrier();
    asm volatile("" ::: "memory");

    for (int t = 0; t < NK; ++t) {
        const int c = t & 1;
        const _Float16* sAc = sA + c * 16384;
        const _Float16* sBc = sB + c * 16384;
        _Float16* sAn = sA + (c ^ 1) * 16384;
        _Float16* sBn = sB + (c ^ 1) * 16384;
        const bool pref = (t + 1 < NK);

        if (pref) {
            const _Float16* gAn = gA + (size_t)(t + 1) * 64;
            const _Float16* gBn = gB + (size_t)(t + 1) * 64;
#pragma unroll
            for (int g = 0; g < 8; g++) gl16(gBn + (size_t)(32 * g) * K, sBn + g * 2048 + ldsw);
#pragma unroll
            for (int g = 0; g < 8; g++) gl16(gAn + (size_t)(32 * g) * K, sAn + g * 2048 + ldsw);
        }

        // ks-outer sweep: per ks load 8 B-frags (32 VGPR) once, stream A with
        // a 2-slot ping-pong; per acc element order is k0 then k1 (unchanged).
#pragma unroll
        for (int ks = 0; ks < 2; ++ks) {
            const int ck = ks ? cA1 : cA0;
            f16x8 bfr[8];
#pragma unroll
            for (int j = 0; j < 8; j++)
                bfr[j] = *(const f16x8*)(sBc + (bRow + j * 16) * 64 + ck);
            f16x8 a[2];
            a[0] = *(const f16x8*)(sAc + aRow * 64 + ck);
#pragma unroll
            for (int i = 0; i < 8; ++i) {
                const int cur = i & 1, nxt = cur ^ 1;
                if (i < 7)
                    a[nxt] = *(const f16x8*)(sAc + (aRow + (i + 1) * 16) * 64 + ck);
                __builtin_amdgcn_sched_barrier(0);
#pragma unroll
                for (int j = 0; j < 8; j++)
                    acc[i][j] = __builtin_amdgcn_mfma_f32_16x16x32_f16(
                        a[cur], bfr[j], acc[i][j], 0, 0, 0);
            }
        }

        asm volatile("s_waitcnt vmcnt(0)" ::: "memory");
        __builtin_amdgcn_s_barrier();
        asm volatile("" ::: "memory");
    }

    // epilogue: +bias, relu, q_e4m3 -> two 128-row swizzled f16 half-tiles
    // through 64KB of LDS -> cvt to e4m3 bytes, coalesced 16B-chunk stores.
    const int col0 = n0 + wc * 128 + fr;
    float bv[8];
#pragma unroll
    for (int j = 0; j < 8; j++) bv[j] = bias[col0 + j * 16];
    const int sub = (fr & 7) * 2;
    const int slotbase = wc * 16 + (fr >> 3);
    const int rowrel0 = kq * 4;
#pragma unroll
    for (int half = 0; half < 2; ++half) {
        if (wr == half) {
#pragma unroll
            for (int i = 0; i < 8; i++) {
                const int trow0 = rowrel0 + i * 16;
#pragma unroll
                for (int r = 0; r < 4; r++) {
                    const int trow = trow0 + r;
                    const int swz = ((kq & 1) * 4 + r) ^ (kq >> 1);  // (trow&7)^((trow>>3)&1)
#pragma unroll
                    for (int j = 0; j < 8; j++) {
                        float v = fmaxf(acc[i][j][r] + bv[j], 0.0f);
                        _Float16 q = q_e4m3_pos(v);
                        int byte = trow * 512 + (((slotbase + j * 2) ^ swz) << 4) + sub;
                        *(_Float16*)((char*)smem + byte) = q;
                    }
                }
            }
        }
        __syncthreads();
#pragma unroll
        for (int cch = 0; cch < 16; cch++) {
            int flat = cch * 256 + tid;          // 16B-chunk index, 4096 per half
            int row  = flat >> 5;                // 0..127
            int slot = flat & 31;
            int swz  = (row & 7) ^ ((row >> 3) & 1);
            f16x8 v8 = *(const f16x8*)((char*)smem + row * 512 + ((slot ^ swz) << 4));
            uint32_t u0 = __builtin_amdgcn_cvt_pk_fp8_f32((float)v8[0], (float)v8[1], 0, false);
            u0 = __builtin_amdgcn_cvt_pk_fp8_f32((float)v8[2], (float)v8[3], u0, true);
            uint32_t u1 = __builtin_amdgcn_cvt_pk_fp8_f32((float)v8[4], (float)v8[5], 0, false);
            u1 = __builtin_amdgcn_cvt_pk_fp8_f32((float)v8[6], (float)v8[7], u1, true);
            uint2 u = {u0, u1};
            *(uint2*)(Cq + (size_t)(m0 + half * 128 + row) * N + n0 + slot * 8) = u;
        }
        if (half == 0) __syncthreads();
    }
}

// ---- GEMM2: out = hq @ wq^T + b2q (MX-fp8, unit scales), q_e5m10, fp32 out ----
// 256x256 tile, BK=128 bytes (one K-step/tile), 4 waves of 128x128. Dbuf 128KB.
__global__ __launch_bounds__(256) void gemm2_fp8(
    const uint8_t* __restrict__ A, const uint8_t* __restrict__ B,
    const float* __restrict__ b2, float* __restrict__ C)
{
    constexpr int Kb = H_DIM;  // 4096 bytes per row
    constexpr int N  = D_DIM;  // 1024
    __shared__ __align__(16) uint8_t smem[131072];
    uint8_t* sA = smem;            // 2 x 32768
    uint8_t* sB = smem + 65536;    // 2 x 32768

    const int tid  = threadIdx.x;
    const int lane = tid & 63;
    const int w    = tid >> 6;             // 4 waves
    const int wr   = w >> 1, wc = w & 1;   // per-wave C: 128 rows x 128 cols
    const int fr   = lane & 15, kq = lane >> 4;

    constexpr int NBX = N / 256;               // 4
    constexpr int NWG = (M_TOT / 256) * NBX;   // 256
    constexpr int CPX = NWG / 8;
    int bid = blockIdx.y * NBX + blockIdx.x;
    bid = (bid & 7) * CPX + (bid >> 3);
    const int n0 = (bid % NBX) * 256;
    const int m0 = (bid / NBX) * 256;

    // staging: round = 32 rows x 128B = 4KB; 8 rounds per operand per tile.
    const int srow = tid >> 3;
    const int sseg = (tid & 7) ^ (srow & 7);     // 16B-slot pre-swizzle
    const uint8_t* gA = A + (size_t)(m0 + srow) * Kb + sseg * 16;
    const uint8_t* gB = B + (size_t)(n0 + srow) * Kb + sseg * 16;
    const int ldsw = w * 1024;                   // bytes per wave per round

    const int xorv = fr & 7;
    const int sO0 = ((2 * kq) ^ xorv) * 16;
    const int sO1 = ((2 * kq + 1) ^ xorv) * 16;
    const int aRowB = (wr * 128 + fr) * 128;
    const int bRowB = (wc * 128 + fr) * 128;

    f32x4 acc[8][8];
#pragma unroll
    for (int i = 0; i < 8; i++)
#pragma unroll
        for (int j = 0; j < 8; j++) acc[i][j] = (f32x4){0.f, 0.f, 0.f, 0.f};

    constexpr int NK = Kb / 128;   // 32
    constexpr uint32_t SC1 = 0x7f7f7f7fu;   // e8m0 unit scale in every byte

#pragma unroll
    for (int g = 0; g < 8; g++) gl16(gB + (size_t)(32 * g) * Kb, sB + g * 4096 + ldsw);
#pragma unroll
    for (int g = 0; g < 8; g++) gl16(gA + (size_t)(32 * g) * Kb, sA + g * 4096 + ldsw);
    asm volatile("s_waitcnt vmcnt(0)" ::: "memory");
    __builtin_amdgcn_s_barrier();
    asm volatile("" ::: "memory");

    for (int t = 0; t < NK; ++t) {
        const int c = t & 1;
        const uint8_t* sAc = sA + c * 32768;
        const uint8_t* sBc = sB + c * 32768;
        uint8_t* sAn = sA + (c ^ 1) * 32768;
        uint8_t* sBn = sB + (c ^ 1) * 32768;
        const bool pref = (t + 1 < NK);

        if (pref) {
            const uint8_t* gAn = gA + (size_t)(t + 1) * 128;
            const uint8_t* gBn = gB + (size_t)(t + 1) * 128;
#pragma unroll
            for (int g = 0; g < 8; g++) gl16(gBn + (size_t)(32 * g) * Kb, sBn + g * 4096 + ldsw);
#pragma unroll
            for (int g = 0; g < 8; g++) gl16(gAn + (size_t)(32 * g) * Kb, sAn + g * 4096 + ldsw);
        }

        // 8 B-frags resident (64 VGPR), A streamed with 2-slot ping-pong.
        i32x8 bfr[8];
#pragma unroll
        for (int j = 0; j < 8; j++) {
            const uint8_t* rb = sBc + bRowB + j * 2048;
            i32x4 lo = *(const i32x4*)(rb + sO0);
            i32x4 hi = *(const i32x4*)(rb + sO1);
            bfr[j] = (i32x8){lo.x, lo.y, lo.z, lo.w, hi.x, hi.y, hi.z, hi.w};
        }
        i32x8 a[2];
        {
            const uint8_t* ra = sAc + aRowB;
            i32x4 lo = *(const i32x4*)(ra + sO0);
            i32x4 hi = *(const i32x4*)(ra + sO1);
            a[0] = (i32x8){lo.x, lo.y, lo.z, lo.w, hi.x, hi.y, hi.z, hi.w};
        }
#pragma unroll
        for (int i = 0; i < 8; ++i) {
            const int cur = i & 1, nxt = cur ^ 1;
            if (i < 7) {
                const uint8_t* ra = sAc + aRowB + (i + 1) * 2048;
                i32x4 lo = *(const i32x4*)(ra + sO0);
                i32x4 hi = *(const i32x4*)(ra + sO1);
                a[nxt] = (i32x8){lo.x, lo.y, lo.z, lo.w, hi.x, hi.y, hi.z, hi.w};
            }
            __builtin_amdgcn_sched_barrier(0);
#pragma unroll
            for (int j = 0; j < 8; j++)
                acc[i][j] = __builtin_amdgcn_mfma_scale_f32_16x16x128_f8f6f4(
                    a[cur], bfr[j], acc[i][j],
                    0, 0,            // cbsz=FP8, blgp=FP8
                    0, SC1,          // opsel_a, scale_a (1.0)
                    0, SC1);         // opsel_b, scale_b (1.0)
        }

        asm volatile("s_waitcnt vmcnt(0)" ::: "memory");
        __builtin_amdgcn_s_barrier();
        asm volatile("" ::: "memory");
    }

    // epilogue: + q_e5m10(b2), quantize e5m10 (f16 RNE roundtrip), store fp32
    const int col0 = n0 + wc * 128 + fr;
    const int row0 = m0 + wr * 128 + kq * 4;
#pragma unroll
    for (int j = 0; j < 8; j++) {
        const float bq = (float)(_Float16)b2[col0 + j * 16];
#pragma unroll
        for (int i = 0; i < 8; i++) {
            size_t base = (size_t)(row0 + i * 16) * N + (col0 + j * 16);
#pragma unroll
            for (int r = 0; r < 4; r++) {
                float v = acc[i][j][r] + bq;
                C[base + (size_t)r * N] = (float)(_Float16)v;
            }
        }
    }
}

extern "C" void kernel_launch(void* const* d_in, const int* in_sizes, int n_in,
                              void* d_out, int out_size, void* d_ws, size_t ws_size,
                              hipStream_t stream) {
    const float* x  = (const float*)d_in[0];   // [16384,1024]
    const float* w1 = (const float*)d_in[1];   // [4096,1024]
    const float* b1 = (const float*)d_in[2];   // [4096]
    const float* w2 = (const float*)d_in[3];   // [1024,4096]
    const float* b2 = (const float*)d_in[4];   // [1024]
    float* out = (float*)d_out;

    // workspace layout (bytes):
    // hq  e4m3 bytes [16384,4096] :  67,108,864
    // xh  f16 [16384,1024]        :  33,554,432
    // w1h f16 [4096,1024]         :   8,388,608
    // wq  e4m3 bytes [1024,4096]  :   4,194,304
    const size_t need = 67108864ull + 33554432ull + 8388608ull + 4194304ull;
    if (ws_size < need) return;  // fail visibly (output stays zero)

    char* ws = (char*)d_ws;
    uint8_t*  hq  = (uint8_t*)ws;
    _Float16* xh  = (_Float16*)(ws + 67108864ull);
    _Float16* w1h = xh + 16777216;
    uint8_t*  wq  = (uint8_t*)(w1h + 4194304);

    cvt_f16_kernel<<<16384, 256, 0, stream>>>(x, xh, 4194304);
    cvt_f16_kernel<<<4096, 256, 0, stream>>>(w1, w1h, 1048576);
    quant_e4m3_byte_kernel<<<4096, 256, 0, stream>>>(w2, (uint32_t*)wq, 1048576);

    // GEMM1: M=16384, N=4096, K=1024 -> grid (16,64) = 1024 wg, 256 threads
    gemm1_f16<<<dim3(H_DIM / 256, M_TOT / 256), 256, 0, stream>>>(xh, w1h, b1, hq);
    // GEMM2: M=16384, N=1024, K=4096 bytes -> grid (4,64) = 256 wg, 256 threads
    gemm2_fp8<<<dim3(D_DIM / 256, M_TOT / 256), 256, 0, stream>>>(hq, wq, b2, out);
}

// Round 12
// 225.354 us; speedup vs baseline: 1.2633x; 1.2633x over previous
//
#include <hip/hip_runtime.h>
#include <stdint.h>

// FFN: x[16384,1024] -> relu(x@W1^T+b1)[16384,4096] -> q_e4m3 -> @W2^T+b2 -> q_e5m10
// Round 14: revert to round-12 (best, 228.8us) + fuse the 3 pre-passes into 1
// launch. r13 post-mortem: 128x128 waves @1 wave/SIMD exposed all LDS latency
// (occupancy 11%, MfmaUtil 28%) — TLP is required to run LDS at rate; r10's
// 128x256 tile / 64x64 waves / 2 blocks/CU is the measured optimum of the
// traffic-vs-latency tradeoff. Structure: single-buffer LDS, barrier-light
// K-loop {compute -> bar -> stage -> vmcnt(0) -> bar}, no setprio,
// sched_barrier(0) read pin, XCD-swizzle, MX-fp8 GEMM2 (unit scales),
// e4m3-byte hq/wq, division-free quant + LDS-transpose epilogue on GEMM1.

#define M_TOT 16384
#define D_DIM 1024
#define H_DIM 4096

typedef _Float16 f16x8 __attribute__((ext_vector_type(8)));
typedef _Float16 f16x4 __attribute__((ext_vector_type(4)));
typedef float f32x4 __attribute__((ext_vector_type(4)));
typedef int i32x4 __attribute__((ext_vector_type(4)));
typedef int i32x8 __attribute__((ext_vector_type(8)));

// global -> LDS direct copy, 16B per lane. LDS dest = wave-uniform base + lane*16.
__device__ __forceinline__ void gl16(const void* g, void* l) {
    __builtin_amdgcn_global_load_lds(
        (const __attribute__((address_space(1))) unsigned int*)(uintptr_t)g,
        (__attribute__((address_space(3))) unsigned int*)(unsigned int)(uintptr_t)l,
        16, 0, 0);
}

// positive-input e4m3 quantize (post-relu), division-free, RNE. Returns the
// quantized VALUE as f16 (exactly representable).
__device__ __forceinline__ _Float16 q_e4m3_pos(float v) {
    uint32_t t = __float_as_uint(v);
    uint32_t tn = (t + 0x7ffffu + ((t >> 20) & 1u)) & 0xfff00000u;
    float qn = __uint_as_float(tn);
    float qs = rintf(v * 512.0f) * 0.001953125f;
    return (_Float16)(v < 0.015625f ? qs : qn);
}

// ---- fused pre-pass: one launch covering
//   blocks [0,16384)      : x  fp32 -> f16 (RNE), x4 vectorized
//   blocks [16384,20480)  : w1 fp32 -> f16 (RNE)
//   blocks [20480,24576)  : w2 fp32 -> e4m3 BYTES via HW cvt (RNE, OCP grid)
// Branch is block-uniform -> no divergence. Same per-element math as before.
__global__ __launch_bounds__(256) void prepass_kernel(
    const float* __restrict__ x,  _Float16* __restrict__ xh,
    const float* __restrict__ w1, _Float16* __restrict__ w1h,
    const float* __restrict__ w2, uint32_t* __restrict__ wq)
{
    const int b = blockIdx.x;
    if (b < 16384) {
        int i = b * 256 + threadIdx.x;            // 4,194,304 quads exactly
        float4 v = reinterpret_cast<const float4*>(x)[i];
        f16x4 hv = {(_Float16)v.x, (_Float16)v.y, (_Float16)v.z, (_Float16)v.w};
        reinterpret_cast<f16x4*>(xh)[i] = hv;
    } else if (b < 20480) {
        int i = (b - 16384) * 256 + threadIdx.x;  // 1,048,576 quads exactly
        float4 v = reinterpret_cast<const float4*>(w1)[i];
        f16x4 hv = {(_Float16)v.x, (_Float16)v.y, (_Float16)v.z, (_Float16)v.w};
        reinterpret_cast<f16x4*>(w1h)[i] = hv;
    } else {
        int i = (b - 20480) * 256 + threadIdx.x;  // 1,048,576 quads exactly
        float4 v = reinterpret_cast<const float4*>(w2)[i];
        uint32_t r = __builtin_amdgcn_cvt_pk_fp8_f32(v.x, v.y, 0, false);
        r = __builtin_amdgcn_cvt_pk_fp8_f32(v.z, v.w, r, true);
        wq[i] = r;
    }
}

// ---- GEMM1: h=relu(xh@w1h^T+b1), q_e4m3, store BYTES. 128x256 BK=64 f16. ----
// 8 waves (2M x 4N) of 64x64; acc=64 regs; single-buffer 48KB staging inside a
// 64KB LDS block (epilogue transpose uses all 64KB). 2 blocks/CU.
__global__ __launch_bounds__(512, 4) void gemm1_f16(
    const _Float16* __restrict__ A, const _Float16* __restrict__ B,
    const float* __restrict__ bias, uint8_t* __restrict__ Cq)
{
    constexpr int K = D_DIM;   // 1024
    constexpr int N = H_DIM;   // 4096 (bytes per out row)
    __shared__ __align__(16) _Float16 smem[32768];   // 64 KiB
    _Float16* sA = smem;            // [128][64] = 8192 f16 (16KB)
    _Float16* sB = smem + 8192;     // [256][64] = 16384 f16 (32KB)

    const int tid  = threadIdx.x;
    const int lane = tid & 63;
    const int w    = tid >> 6;
    const int wr   = w >> 2, wc = w & 3;   // per-wave C: 64 rows x 64 cols
    const int fr   = lane & 15, kq = lane >> 4;

    constexpr int NBX = N / 256;               // 16
    constexpr int NWG = (M_TOT / 128) * NBX;   // 2048
    constexpr int CPX = NWG / 8;
    int bid = blockIdx.y * NBX + blockIdx.x;
    bid = (bid & 7) * CPX + (bid >> 3);
    const int n0 = (bid % NBX) * 256;
    const int m0 = (bid / NBX) * 128;

    // staging: round = 64 rows x 128B = 8KB; A: 2 rounds, B: 4 rounds.
    const int srow = tid >> 3;
    const int sseg = (tid & 7) ^ (srow & 7);
    const _Float16* gA = A + (size_t)(m0 + srow) * K + sseg * 8;
    const _Float16* gB = B + (size_t)(n0 + srow) * K + sseg * 8;
    const int ldsw = w * 512;                        // f16 per wave per round
    const size_t R1 = (size_t)64 * K, R2 = (size_t)128 * K, R3 = (size_t)192 * K;

    const int xorv = fr & 7;
    const int cA0 = (kq ^ xorv) * 8;
    const int cA1 = ((kq + 4) ^ xorv) * 8;
    const int aRow = wr * 64 + fr;
    const int bRow = wc * 64 + fr;

    f32x4 acc[4][4];
#pragma unroll
    for (int i = 0; i < 4; i++)
#pragma unroll
        for (int j = 0; j < 4; j++) acc[i][j] = (f32x4){0.f, 0.f, 0.f, 0.f};

    f16x8 bfr[4][2];
    constexpr int NK = K / 64;   // 16

    // prologue: stage tile 0 (B r0-3, A r0-1), drain, barrier.
    gl16(gB,      sB + ldsw);
    gl16(gB + R1, sB + 4096 + ldsw);
    gl16(gB + R2, sB + 8192 + ldsw);
    gl16(gB + R3, sB + 12288 + ldsw);
    gl16(gA,      sA + ldsw);
    gl16(gA + R1, sA + 4096 + ldsw);
    asm volatile("s_waitcnt vmcnt(0)" ::: "memory");
    __builtin_amdgcn_s_barrier();
    asm volatile("" ::: "memory");

    for (int t = 0; t < NK; ++t) {
        // ---- compute tile t from the single buffer ----
#pragma unroll
        for (int j = 0; j < 4; j++) {
            const _Float16* rb = sB + (bRow + j * 16) * 64;
            bfr[j][0] = *(const f16x8*)(rb + cA0);
            bfr[j][1] = *(const f16x8*)(rb + cA1);
        }
        f16x8 afr[2][2];
        {
            const _Float16* ra = sA + aRow * 64;
            afr[0][0] = *(const f16x8*)(ra + cA0);
            afr[0][1] = *(const f16x8*)(ra + cA1);
        }
#pragma unroll
        for (int i = 0; i < 4; ++i) {
            const int cur = i & 1, nxt = cur ^ 1;
            if (i < 3) {
                const _Float16* ra = sA + (aRow + (i + 1) * 16) * 64;
                afr[nxt][0] = *(const f16x8*)(ra + cA0);
                afr[nxt][1] = *(const f16x8*)(ra + cA1);
            }
            __builtin_amdgcn_sched_barrier(0);
#pragma unroll
            for (int j = 0; j < 4; j++) {
                acc[i][j] = __builtin_amdgcn_mfma_f32_16x16x32_f16(
                    afr[cur][0], bfr[j][0], acc[i][j], 0, 0, 0);
                acc[i][j] = __builtin_amdgcn_mfma_f32_16x16x32_f16(
                    afr[cur][1], bfr[j][1], acc[i][j], 0, 0, 0);
            }
        }
        // all waves done reading tile t
        asm volatile("" ::: "memory");
        __builtin_amdgcn_s_barrier();
        asm volatile("" ::: "memory");

        if (t + 1 < NK) {
            // stage tile t+1 into the same buffer; the drain is dead time for
            // THIS block, covered by the co-resident partner block's compute.
            const _Float16* gAn = gA + (size_t)(t + 1) * 64;
            const _Float16* gBn = gB + (size_t)(t + 1) * 64;
            gl16(gBn,      sB + ldsw);
            gl16(gBn + R1, sB + 4096 + ldsw);
            gl16(gBn + R2, sB + 8192 + ldsw);
            gl16(gBn + R3, sB + 12288 + ldsw);
            gl16(gAn,      sA + ldsw);
            gl16(gAn + R1, sA + 4096 + ldsw);
            asm volatile("s_waitcnt vmcnt(0)" ::: "memory");
            __builtin_amdgcn_s_barrier();
            asm volatile("" ::: "memory");
        }
    }

    // epilogue: +bias, relu, q_e4m3 (f16 value) -> swizzled 64KB LDS tile
    // [128][256] f16 -> read f16x8, cvt to e4m3 bytes, coalesced 16B stores.
    const int col0 = n0 + wc * 64 + fr;
    float bv[4];
#pragma unroll
    for (int j = 0; j < 4; j++) bv[j] = bias[col0 + j * 16];
    const int sub = (fr & 7) * 2;
    const int slotbase = wc * 8 + (fr >> 3);
    const int rowbase = wr * 64 + kq * 4;
#pragma unroll
    for (int i = 0; i < 4; i++) {
        const int trow0 = rowbase + i * 16;
#pragma unroll
        for (int r = 0; r < 4; r++) {
            const int trow = trow0 + r;
            const int swz = ((kq & 1) * 4 + r) ^ (kq >> 1);  // == (trow&7)^((trow>>3)&1)
#pragma unroll
            for (int j = 0; j < 4; j++) {
                float v = fmaxf(acc[i][j][r] + bv[j], 0.0f);
                _Float16 q = q_e4m3_pos(v);
                int byte = trow * 512 + (((slotbase + j * 2) ^ swz) << 4) + sub;
                *(_Float16*)((char*)smem + byte) = q;
            }
        }
    }
    __syncthreads();
#pragma unroll
    for (int cch = 0; cch < 8; cch++) {
        int flat = cch * 512 + tid;          // 16B-chunk index, 4096 total
        int row  = flat >> 5;                // 0..127
        int slot = flat & 31;
        int swz  = (row & 7) ^ ((row >> 3) & 1);
        f16x8 v8 = *(const f16x8*)((char*)smem + row * 512 + ((slot ^ swz) << 4));
        uint32_t u0 = __builtin_amdgcn_cvt_pk_fp8_f32((float)v8[0], (float)v8[1], 0, false);
        u0 = __builtin_amdgcn_cvt_pk_fp8_f32((float)v8[2], (float)v8[3], u0, true);
        uint32_t u1 = __builtin_amdgcn_cvt_pk_fp8_f32((float)v8[4], (float)v8[5], 0, false);
        u1 = __builtin_amdgcn_cvt_pk_fp8_f32((float)v8[6], (float)v8[7], u1, true);
        uint2 u = {u0, u1};
        *(uint2*)(Cq + (size_t)(m0 + row) * N + n0 + slot * 8) = u;
    }
}

// ---- GEMM2: out = hq @ wq^T + b2q (MX-fp8, unit scales), q_e5m10, fp32 out ----
// 128x256 tile, BK=128 bytes, 8 waves of 64x64; acc=64; 48KB single-buffer LDS;
// 2 blocks/CU. Grid (4,128) = 512 wg.
__global__ __launch_bounds__(512, 4) void gemm2_fp8(
    const uint8_t* __restrict__ A, const uint8_t* __restrict__ B,
    const float* __restrict__ b2, float* __restrict__ C)
{
    constexpr int Kb = H_DIM;  // 4096 bytes per row
    constexpr int N  = D_DIM;  // 1024
    __shared__ __align__(16) uint8_t smem[49152];    // 48 KiB
    uint8_t* sA = smem;            // [128][128B] = 16KB
    uint8_t* sB = smem + 16384;    // [256][128B] = 32KB

    const int tid  = threadIdx.x;
    const int lane = tid & 63;
    const int w    = tid >> 6;
    const int wr   = w >> 2, wc = w & 3;   // per-wave C: 64 rows x 64 cols
    const int fr   = lane & 15, kq = lane >> 4;

    constexpr int NBX = N / 256;               // 4
    constexpr int NWG = (M_TOT / 128) * NBX;   // 512
    constexpr int CPX = NWG / 8;
    int bid = blockIdx.y * NBX + blockIdx.x;
    bid = (bid & 7) * CPX + (bid >> 3);
    const int n0 = (bid % NBX) * 256;
    const int m0 = (bid / NBX) * 128;

    const int srow = tid >> 3;
    const int sseg = (tid & 7) ^ (srow & 7);     // 16B-slot pre-swizzle
    const uint8_t* gA = A + (size_t)(m0 + srow) * Kb + sseg * 16;
    const uint8_t* gB = B + (size_t)(n0 + srow) * Kb + sseg * 16;
    const int ldsw = w * 1024;                   // bytes per wave per round
    const size_t R1 = (size_t)64 * Kb, R2 = (size_t)128 * Kb, R3 = (size_t)192 * Kb;

    const int xorv = fr & 7;
    const int sO0 = ((2 * kq) ^ xorv) * 16;
    const int sO1 = ((2 * kq + 1) ^ xorv) * 16;
    const int aRowB = (wr * 64 + fr) * 128;
    const int bRowB = (wc * 64 + fr) * 128;

    f32x4 acc[4][4];
#pragma unroll
    for (int i = 0; i < 4; i++)
#pragma unroll
        for (int j = 0; j < 4; j++) acc[i][j] = (f32x4){0.f, 0.f, 0.f, 0.f};

    i32x8 bfr[4];
    constexpr int NK = Kb / 128;   // 32
    constexpr uint32_t SC1 = 0x7f7f7f7fu;   // e8m0 unit scale in every byte

    gl16(gB,      sB + ldsw);
    gl16(gB + R1, sB + 8192 + ldsw);
    gl16(gB + R2, sB + 16384 + ldsw);
    gl16(gB + R3, sB + 24576 + ldsw);
    gl16(gA,      sA + ldsw);
    gl16(gA + R1, sA + 8192 + ldsw);
    asm volatile("s_waitcnt vmcnt(0)" ::: "memory");
    __builtin_amdgcn_s_barrier();
    asm volatile("" ::: "memory");

    for (int t = 0; t < NK; ++t) {
        // ---- compute tile t ----
#pragma unroll
        for (int j = 0; j < 4; j++) {
            const uint8_t* rb = sB + bRowB + j * 2048;
            i32x4 lo = *(const i32x4*)(rb + sO0);
            i32x4 hi = *(const i32x4*)(rb + sO1);
            bfr[j] = (i32x8){lo.x, lo.y, lo.z, lo.w, hi.x, hi.y, hi.z, hi.w};
        }
#pragma unroll
        for (int i = 0; i < 4; ++i) {
            const uint8_t* ra = sA + aRowB + i * 2048;
            i32x4 lo = *(const i32x4*)(ra + sO0);
            i32x4 hi = *(const i32x4*)(ra + sO1);
            i32x8 af = (i32x8){lo.x, lo.y, lo.z, lo.w, hi.x, hi.y, hi.z, hi.w};
            __builtin_amdgcn_sched_barrier(0);
#pragma unroll
            for (int j = 0; j < 4; j++) {
                acc[i][j] = __builtin_amdgcn_mfma_scale_f32_16x16x128_f8f6f4(
                    af, bfr[j], acc[i][j],
                    0, 0,            // cbsz=FP8, blgp=FP8
                    0, SC1,          // opsel_a, scale_a (1.0)
                    0, SC1);         // opsel_b, scale_b (1.0)
            }
        }
        asm volatile("" ::: "memory");
        __builtin_amdgcn_s_barrier();
        asm volatile("" ::: "memory");

        if (t + 1 < NK) {
            const uint8_t* gAn = gA + (size_t)(t + 1) * 128;
            const uint8_t* gBn = gB + (size_t)(t + 1) * 128;
            gl16(gBn,      sB + ldsw);
            gl16(gBn + R1, sB + 8192 + ldsw);
            gl16(gBn + R2, sB + 16384 + ldsw);
            gl16(gBn + R3, sB + 24576 + ldsw);
            gl16(gAn,      sA + ldsw);
            gl16(gAn + R1, sA + 8192 + ldsw);
            asm volatile("s_waitcnt vmcnt(0)" ::: "memory");
            __builtin_amdgcn_s_barrier();
            asm volatile("" ::: "memory");
        }
    }

    // epilogue: + q_e5m10(b2), quantize e5m10 (f16 RNE roundtrip), store fp32
    const int col0 = n0 + wc * 64 + fr;
    const int row0 = m0 + wr * 64 + kq * 4;
#pragma unroll
    for (int j = 0; j < 4; j++) {
        const float bq = (float)(_Float16)b2[col0 + j * 16];
#pragma unroll
        for (int i = 0; i < 4; i++) {
            size_t base = (size_t)(row0 + i * 16) * N + (col0 + j * 16);
#pragma unroll
            for (int r = 0; r < 4; r++) {
                float v = acc[i][j][r] + bq;
                C[base + (size_t)r * N] = (float)(_Float16)v;
            }
        }
    }
}

extern "C" void kernel_launch(void* const* d_in, const int* in_sizes, int n_in,
                              void* d_out, int out_size, void* d_ws, size_t ws_size,
                              hipStream_t stream) {
    const float* x  = (const float*)d_in[0];   // [16384,1024]
    const float* w1 = (const float*)d_in[1];   // [4096,1024]
    const float* b1 = (const float*)d_in[2];   // [4096]
    const float* w2 = (const float*)d_in[3];   // [1024,4096]
    const float* b2 = (const float*)d_in[4];   // [1024]
    float* out = (float*)d_out;

    // workspace layout (bytes):
    // hq  e4m3 bytes [16384,4096] :  67,108,864
    // xh  f16 [16384,1024]        :  33,554,432
    // w1h f16 [4096,1024]         :   8,388,608
    // wq  e4m3 bytes [1024,4096]  :   4,194,304
    const size_t need = 67108864ull + 33554432ull + 8388608ull + 4194304ull;
    if (ws_size < need) return;  // fail visibly (output stays zero)

    char* ws = (char*)d_ws;
    uint8_t*  hq  = (uint8_t*)ws;
    _Float16* xh  = (_Float16*)(ws + 67108864ull);
    _Float16* w1h = xh + 16777216;
    uint8_t*  wq  = (uint8_t*)(w1h + 4194304);

    // fused pre-pass: x->f16, w1->f16, w2->e4m3 bytes in ONE launch
    prepass_kernel<<<24576, 256, 0, stream>>>(x, xh, w1, w1h, w2, (uint32_t*)wq);

    // GEMM1: M=16384, N=4096, K=1024 -> grid (16,128) = 2048 wg, 2 blocks/CU
    gemm1_f16<<<dim3(H_DIM / 256, M_TOT / 128), 512, 0, stream>>>(xh, w1h, b1, hq);
    // GEMM2: M=16384, N=1024, K=4096 bytes -> grid (4,128) = 512 wg, 2 blocks/CU
    gemm2_fp8<<<dim3(D_DIM / 256, M_TOT / 128), 512, 0, stream>>>(hq, wq, b2, out);
}